// Round 7
// baseline (426.147 us; speedup 1.0000x reference)
//
#include <hip/hip_runtime.h>

#define TT 2048
#define NV 1000
#define LOG2E 1.4426950408889634f

typedef float v2f __attribute__((ext_vector_type(2)));

static __device__ __forceinline__ v2f sp(float x) { return (v2f){x, x}; }
static __device__ __forceinline__ v2f pkfma(v2f a, v2f b, v2f c) {
    return __builtin_elementwise_fma(a, b, c);
}

// ---- XLA/Eigen f32 tanh, scalar, VERBATIM (numerics-critical; R1 vs R2). ----
// Used ONLY for g-gate and cell tanh (the cancellation-sensitive spots).
__device__ __forceinline__ float tanh_f32(float x) {
    const float L = 7.90531110763549805f;
    x = fminf(fmaxf(x, -L), L);
    float x2 = x * x;
    float p = -2.76076847742355e-16f;
    p = __builtin_fmaf(p, x2, 2.00018790482477e-13f);
    p = __builtin_fmaf(p, x2, -8.60467152213735e-11f);
    p = __builtin_fmaf(p, x2, 5.12229709037114e-08f);
    p = __builtin_fmaf(p, x2, 1.48572235717979e-05f);
    p = __builtin_fmaf(p, x2, 6.37261928875436e-04f);
    p = __builtin_fmaf(p, x2, 4.89352455891786e-03f);
    float q = 1.19825839466702e-06f;
    q = __builtin_fmaf(q, x2, 1.18534705686654e-04f);
    q = __builtin_fmaf(q, x2, 2.26843463243900e-03f);
    q = __builtin_fmaf(q, x2, 4.89352518554385e-03f);
    float r = __builtin_amdgcn_rcpf(q);
    r = __builtin_fmaf(__builtin_fmaf(-q, r, 1.0f), r, r);  // Newton: <=1 ulp
    return (x * p) * r;
}

// DPP cross-lane within the 8-lane group (j = lane&7):
//   quad_perm xor1/2/3 (exact); row_half_mirror = lane -> 7-lane within each
//   8-half == exact xor7; xor4/5/6 = quad_perm(xor7(.)). All stay in-group.
template <int CTRL>
__device__ __forceinline__ float dppf(float x) {
    return __int_as_float(__builtin_amdgcn_update_dpp(
        0, __float_as_int(x), CTRL, 0xF, 0xF, true));
}
#define DPP_XOR1 0xB1   // quad_perm [1,0,3,2]
#define DPP_XOR2 0x4E   // quad_perm [2,3,0,1]
#define DPP_XOR3 0x1B   // quad_perm [3,2,1,0]
#define DPP_HMIR 0x141  // row_half_mirror == xor7 within 8-lane half

// Quartet-local layout: 8 lanes per batch row; lane j owns ALL 4 gates of
// hidden unit j: reg1=(i_j,f_j), reg2=(g_j,o_j). No gate exchange at all;
// tanh(g), tanh(c), sigma each computed exactly once per (row,j).
// Algorithms per gate IDENTICAL to R6 (absmax 0.0): i/f/o via
// rcp(1+exp2(-log2e*pre)); g and c via rational tanh; same xor-m dot pairing,
// same uA/uB even/odd split, same distributed prescales.
// TAB4[v][j] = float4(-log2e*pre_i, -log2e*pre_f, 1.0*pre_g, -log2e*pre_o).
// 128000 B LDS -> 1 block/CU. Block 128 thr = 2 waves = 16 rows; grid 256.
// 32768 threads = 512 waves -> 2 waves/CU on 2 of 4 SIMDs (thread-deficit:
// 4096 rows x 8 lanes; LDS caps 1 block/CU so this is the max spread).
extern "C" __global__ void __launch_bounds__(128, 1)
lstm_fused(const int* __restrict__ x, const float* __restrict__ emb,
           const float* __restrict__ W_ih, const float* __restrict__ W_hh,
           const float* __restrict__ b_ih, const float* __restrict__ b_hh,
           const float* __restrict__ W_cls, const float* __restrict__ b_cls,
           float* __restrict__ out)
{
    extern __shared__ float TAB[];  // float4[1000][8] viewed flat

    const int tid = threadIdx.x;
    const int j   = tid & 7;
    const int grp = tid >> 3;            // row within block (0..15)

    const int gi = j, gf = j + 8, gg = j + 16, go = j + 24;

    // ---- phase 1: build TAB4 (4 gate dots per thread) ----
    {
        float wi[8], wf[8], wg[8], wo[8];
        #pragma unroll
        for (int k = 0; k < 8; ++k) {
            wi[k] = W_ih[gi * 8 + k];
            wf[k] = W_ih[gf * 8 + k];
            wg[k] = W_ih[gg * 8 + k];
            wo[k] = W_ih[go * 8 + k];
        }
        const float bi = b_ih[gi] + b_hh[gi];
        const float bf = b_ih[gf] + b_hh[gf];
        const float bg = b_ih[gg] + b_hh[gg];
        const float bo = b_ih[go] + b_hh[go];
        for (int v = grp; v < NV; v += 16) {
            const float4 e0 = *(const float4*)(emb + v * 8);
            const float4 e1 = *(const float4*)(emb + v * 8 + 4);
            float di = bi + e0.x*wi[0] + e0.y*wi[1] + e0.z*wi[2] + e0.w*wi[3]
                          + e1.x*wi[4] + e1.y*wi[5] + e1.z*wi[6] + e1.w*wi[7];
            float df = bf + e0.x*wf[0] + e0.y*wf[1] + e0.z*wf[2] + e0.w*wf[3]
                          + e1.x*wf[4] + e1.y*wf[5] + e1.z*wf[6] + e1.w*wf[7];
            float dg = bg + e0.x*wg[0] + e0.y*wg[1] + e0.z*wg[2] + e0.w*wg[3]
                          + e1.x*wg[4] + e1.y*wg[5] + e1.z*wg[6] + e1.w*wg[7];
            float do_ = bo + e0.x*wo[0] + e0.y*wo[1] + e0.z*wo[2] + e0.w*wo[3]
                           + e1.x*wo[4] + e1.y*wo[5] + e1.z*wo[6] + e1.w*wo[7];
            ((float4*)TAB)[v * 8 + j] =
                make_float4(-LOG2E * di, -LOG2E * df, 1.0f * dg, -LOG2E * do_);
        }
    }
    __syncthreads();

    // ---- recurrence ----
    const int b = blockIdx.x * 16 + grp;
    const int* __restrict__ xrow = x + (size_t)b * TT;

    // xor-ordered W_hh pairs: w1[m]=(i,f), w2[m]=(g,o), k = j^m pairs with
    // tree output m_k = h_{j^m}. Prescales as TAB (distributed, R6-identical).
    v2f w1[8], w2[8];
    #pragma unroll
    for (int m = 0; m < 8; ++m) {
        const int k = j ^ m;
        w1[m] = (v2f){ -LOG2E * W_hh[gi * 8 + k], -LOG2E * W_hh[gf * 8 + k] };
        w2[m] = (v2f){   1.0f * W_hh[gg * 8 + k], -LOG2E * W_hh[go * 8 + k] };
    }

    float c  = 0.0f;
    float hn = 0.0f;   // lane j: h_j of its row

    int4 iA = *(const int4*)(xrow);
    int4 iB = *(const int4*)(xrow + 4);
    float4 xg0 = ((const float4*)TAB)[iA.x * 8 + j];  // depth-2 prefetch
    float4 xg1 = ((const float4*)TAB)[iA.y * 8 + j];

#define STEP(XG, NIDX) do {                                                      \
        float m1 = dppf<DPP_XOR1>(hn);                                           \
        float m2 = dppf<DPP_XOR2>(hn);                                           \
        float m3 = dppf<DPP_XOR3>(hn);                                           \
        float m7 = dppf<DPP_HMIR>(hn);                                           \
        v2f uA1 = pkfma(w1[0], sp(hn), (v2f){XG.x, XG.y});                       \
        v2f uA2 = pkfma(w2[0], sp(hn), (v2f){XG.z, XG.w});                       \
        v2f uB1 = w1[1] * sp(m1);                                                \
        v2f uB2 = w2[1] * sp(m1);                                                \
        float m6 = dppf<DPP_XOR1>(m7);                                           \
        float m5 = dppf<DPP_XOR2>(m7);                                           \
        float m4 = dppf<DPP_XOR3>(m7);                                           \
        uA1 = pkfma(w1[2], sp(m2), uA1);  uA2 = pkfma(w2[2], sp(m2), uA2);       \
        uB1 = pkfma(w1[3], sp(m3), uB1);  uB2 = pkfma(w2[3], sp(m3), uB2);       \
        uA1 = pkfma(w1[4], sp(m4), uA1);  uA2 = pkfma(w2[4], sp(m4), uA2);       \
        uB1 = pkfma(w1[5], sp(m5), uB1);  uB2 = pkfma(w2[5], sp(m5), uB2);       \
        uA1 = pkfma(w1[6], sp(m6), uA1);  uA2 = pkfma(w2[6], sp(m6), uA2);       \
        uB1 = pkfma(w1[7], sp(m7), uB1);  uB2 = pkfma(w2[7], sp(m7), uB2);       \
        v2f u1 = uA1 + uB1;    /* (u_i, u_f) sigma-prescaled */                  \
        v2f u2 = uA2 + uB2;    /* (u_g raw, u_o sigma-prescaled) */              \
        XG = ((const float4*)TAB)[(NIDX) * 8 + j];   /* prefetch t+2 */          \
        float ei = __builtin_amdgcn_exp2f(u1.x);                                 \
        float ef = __builtin_amdgcn_exp2f(u1.y);                                 \
        float eo = __builtin_amdgcn_exp2f(u2.y);                                 \
        float si = __builtin_amdgcn_rcpf(1.0f + ei);                             \
        float sf = __builtin_amdgcn_rcpf(1.0f + ef);                             \
        float so = __builtin_amdgcn_rcpf(1.0f + eo);                             \
        float tg = tanh_f32(u2.x);                                               \
        c  = __builtin_fmaf(sf, c, si * tg);                                     \
        hn = so * tanh_f32(c);                                                   \
    } while (0)

    for (int t = 0; t < TT; t += 4) {
        const int nb = (t + 8 < TT) ? (t / 4 + 2) : 0;  // clamp tail prefetch
        int4 iN = *(const int4*)(xrow + nb * 4);
        STEP(xg0, iA.z);
        STEP(xg1, iA.w);
        STEP(xg0, iB.x);
        STEP(xg1, iB.y);
        iA = iB; iB = iN;
    }
#undef STEP

    // ---- head: out[b] = 0.5 + 0.5*tanh(0.5*(h.W_cls + b_cls)) ----
    // Lane j==0: hn=h_0, m1..m7 = h_1..h_7 -> same summation order as R2-R6.
    {
        float m1 = dppf<DPP_XOR1>(hn);
        float m2 = dppf<DPP_XOR2>(hn);
        float m3 = dppf<DPP_XOR3>(hn);
        float m7 = dppf<DPP_HMIR>(hn);
        float m6 = dppf<DPP_XOR1>(m7);
        float m5 = dppf<DPP_XOR2>(m7);
        float m4 = dppf<DPP_XOR3>(m7);
        if (j == 0) {
            float z = b_cls[0]
                + hn * W_cls[0] + m1 * W_cls[1] + m2 * W_cls[2] + m3 * W_cls[3]
                + m4 * W_cls[4] + m5 * W_cls[5] + m6 * W_cls[6] + m7 * W_cls[7];
            out[b] = __builtin_fmaf(0.5f, tanh_f32(0.5f * z), 0.5f);
        }
    }
}

extern "C" void kernel_launch(void* const* d_in, const int* in_sizes, int n_in,
                              void* d_out, int out_size, void* d_ws, size_t ws_size,
                              hipStream_t stream)
{
    (void)in_sizes; (void)n_in; (void)d_ws; (void)ws_size; (void)out_size;
    const int*   x     = (const int*)  d_in[0];
    const float* emb   = (const float*)d_in[1];
    const float* W_ih  = (const float*)d_in[2];
    const float* W_hh  = (const float*)d_in[3];
    const float* b_ih  = (const float*)d_in[4];
    const float* b_hh  = (const float*)d_in[5];
    const float* W_cls = (const float*)d_in[6];
    const float* b_cls = (const float*)d_in[7];
    float* out = (float*)d_out;

    const int lds_bytes = NV * 8 * 16;  // 128000 <= 163840 (gfx950 opt-in)
    hipFuncSetAttribute((const void*)lstm_fused,
                        hipFuncAttributeMaxDynamicSharedMemorySize, lds_bytes);

    lstm_fused<<<dim3(256), dim3(128), lds_bytes, stream>>>(
        x, emb, W_ih, W_hh, b_ih, b_hh, W_cls, b_cls, out);
}

// Round 8
// 401.384 us; speedup vs baseline: 1.0617x; 1.0617x over previous
//
#include <hip/hip_runtime.h>

#define TT 2048
#define NV 1000
#define LOG2E 1.4426950408889634f
#define TABSTRIDE 160  // bytes per vocab row (40 floats): breaks 4-way ds bank alias

typedef float v2f __attribute__((ext_vector_type(2)));

static __device__ __forceinline__ v2f sp(float x) { return (v2f){x, x}; }
static __device__ __forceinline__ v2f pkfma(v2f a, v2f b, v2f c) {
    return __builtin_elementwise_fma(a, b, c);
}

// ---- XLA/Eigen f32 tanh, scalar, VERBATIM (numerics-critical; R1 vs R2). ----
// Used ONLY for g-gate and cell tanh (the cancellation-sensitive spots).
__device__ __forceinline__ float tanh_f32(float x) {
    const float L = 7.90531110763549805f;
    x = fminf(fmaxf(x, -L), L);
    float x2 = x * x;
    float p = -2.76076847742355e-16f;
    p = __builtin_fmaf(p, x2, 2.00018790482477e-13f);
    p = __builtin_fmaf(p, x2, -8.60467152213735e-11f);
    p = __builtin_fmaf(p, x2, 5.12229709037114e-08f);
    p = __builtin_fmaf(p, x2, 1.48572235717979e-05f);
    p = __builtin_fmaf(p, x2, 6.37261928875436e-04f);
    p = __builtin_fmaf(p, x2, 4.89352455891786e-03f);
    float q = 1.19825839466702e-06f;
    q = __builtin_fmaf(q, x2, 1.18534705686654e-04f);
    q = __builtin_fmaf(q, x2, 2.26843463243900e-03f);
    q = __builtin_fmaf(q, x2, 4.89352518554385e-03f);
    float r = __builtin_amdgcn_rcpf(q);
    r = __builtin_fmaf(__builtin_fmaf(-q, r, 1.0f), r, r);  // Newton: <=1 ulp
    return (x * p) * r;
}

// DPP cross-lane within the 8-lane group (j = lane&7). All sources stay within
// lanes 0-31 when exec upper half is off (quad_perm + row_half_mirror are
// 8/4-lane local).
template <int CTRL>
__device__ __forceinline__ float dppf(float x) {
    return __int_as_float(__builtin_amdgcn_update_dpp(
        0, __float_as_int(x), CTRL, 0xF, 0xF, true));
}
#define DPP_XOR1 0xB1   // quad_perm [1,0,3,2]
#define DPP_XOR2 0x4E   // quad_perm [2,3,0,1]
#define DPP_XOR3 0x1B   // quad_perm [3,2,1,0]
#define DPP_HMIR 0x141  // row_half_mirror == xor7 within 8-lane half

// HALF-WAVE EXPERIMENT (vs R7: identical per-row math, new lane mapping):
// 256 thr/block = 4 waves; each wave uses lanes 0-31 only (4 rows of 8 lanes),
// upper 32 lanes retire after TAB build -> exec hi-half = 0 for the whole
// recurrence. 1024 waves on 1024 SIMDs. If gfx950 skips exec-empty wave64
// halves (RDNA-style), per-wave issue halves vs R7 -> ~2x. If not, dur ==
// R7 (~430 us) and we learn the fact.
// TAB4[v] at stride 160 B (40 floats): bank rotation (v*40)%32 = 8*(v%4)
// de-aliases the 4 concurrent rows' ds_read_b128 (R7: guaranteed 4-way).
extern "C" __global__ void __launch_bounds__(256, 1)
lstm_fused(const int* __restrict__ x, const float* __restrict__ emb,
           const float* __restrict__ W_ih, const float* __restrict__ W_hh,
           const float* __restrict__ b_ih, const float* __restrict__ b_hh,
           const float* __restrict__ W_cls, const float* __restrict__ b_cls,
           float* __restrict__ out)
{
    extern __shared__ char TABc[];  // 1000 rows x 160 B

    const int tid  = threadIdx.x;
    const int lane = tid & 63;
    const int wv   = tid >> 6;

    // ---- phase 1: build TAB4 with ALL 256 threads (4 gate dots per thread) ----
    {
        const int j2 = tid & 7;
        const int gi = j2, gf = j2 + 8, gg = j2 + 16, go = j2 + 24;
        float wi[8], wf[8], wg[8], wo[8];
        #pragma unroll
        for (int k = 0; k < 8; ++k) {
            wi[k] = W_ih[gi * 8 + k];
            wf[k] = W_ih[gf * 8 + k];
            wg[k] = W_ih[gg * 8 + k];
            wo[k] = W_ih[go * 8 + k];
        }
        const float bi = b_ih[gi] + b_hh[gi];
        const float bf = b_ih[gf] + b_hh[gf];
        const float bg = b_ih[gg] + b_hh[gg];
        const float bo = b_ih[go] + b_hh[go];
        for (int v = (tid >> 3); v < NV; v += 32) {
            const float4 e0 = *(const float4*)(emb + v * 8);
            const float4 e1 = *(const float4*)(emb + v * 8 + 4);
            float di = bi + e0.x*wi[0] + e0.y*wi[1] + e0.z*wi[2] + e0.w*wi[3]
                          + e1.x*wi[4] + e1.y*wi[5] + e1.z*wi[6] + e1.w*wi[7];
            float df = bf + e0.x*wf[0] + e0.y*wf[1] + e0.z*wf[2] + e0.w*wf[3]
                          + e1.x*wf[4] + e1.y*wf[5] + e1.z*wf[6] + e1.w*wf[7];
            float dg = bg + e0.x*wg[0] + e0.y*wg[1] + e0.z*wg[2] + e0.w*wg[3]
                          + e1.x*wg[4] + e1.y*wg[5] + e1.z*wg[6] + e1.w*wg[7];
            float do_ = bo + e0.x*wo[0] + e0.y*wo[1] + e0.z*wo[2] + e0.w*wo[3]
                           + e1.x*wo[4] + e1.y*wo[5] + e1.z*wo[6] + e1.w*wo[7];
            *(float4*)(TABc + v * TABSTRIDE + j2 * 16) =
                make_float4(-LOG2E * di, -LOG2E * df, 1.0f * dg, -LOG2E * do_);
        }
    }
    __syncthreads();

    if (lane >= 32) return;   // hi half-wave idle: exec[63:32]=0 for entire loop

    const int j = lane & 7;
    const int gi = j, gf = j + 8, gg = j + 16, go = j + 24;
    const int grp = wv * 4 + (lane >> 3);          // row within block (0..15)
    const int b   = blockIdx.x * 16 + grp;
    const int* __restrict__ xrow = x + (size_t)b * TT;
    const char* __restrict__ TABj = TABc + j * 16; // fold lane offset once

    // xor-ordered W_hh pairs (identical to R7; validated absmax 0.0).
    v2f w1[8], w2[8];
    #pragma unroll
    for (int m = 0; m < 8; ++m) {
        const int k = j ^ m;
        w1[m] = (v2f){ -LOG2E * W_hh[gi * 8 + k], -LOG2E * W_hh[gf * 8 + k] };
        w2[m] = (v2f){   1.0f * W_hh[gg * 8 + k], -LOG2E * W_hh[go * 8 + k] };
    }

    float c  = 0.0f;
    float hn = 0.0f;   // lane j: h_j of its row

    int4 iA = *(const int4*)(xrow);
    int4 iB = *(const int4*)(xrow + 4);
    float4 xg0 = *(const float4*)(TABj + iA.x * TABSTRIDE);  // depth-2 prefetch
    float4 xg1 = *(const float4*)(TABj + iA.y * TABSTRIDE);

#define STEP(XG, NIDX) do {                                                      \
        float m1 = dppf<DPP_XOR1>(hn);                                           \
        float m2 = dppf<DPP_XOR2>(hn);                                           \
        float m3 = dppf<DPP_XOR3>(hn);                                           \
        float m7 = dppf<DPP_HMIR>(hn);                                           \
        v2f uA1 = pkfma(w1[0], sp(hn), (v2f){XG.x, XG.y});                       \
        v2f uA2 = pkfma(w2[0], sp(hn), (v2f){XG.z, XG.w});                       \
        v2f uB1 = w1[1] * sp(m1);                                                \
        v2f uB2 = w2[1] * sp(m1);                                                \
        float m6 = dppf<DPP_XOR1>(m7);                                           \
        float m5 = dppf<DPP_XOR2>(m7);                                           \
        float m4 = dppf<DPP_XOR3>(m7);                                           \
        uA1 = pkfma(w1[2], sp(m2), uA1);  uA2 = pkfma(w2[2], sp(m2), uA2);       \
        uB1 = pkfma(w1[3], sp(m3), uB1);  uB2 = pkfma(w2[3], sp(m3), uB2);       \
        uA1 = pkfma(w1[4], sp(m4), uA1);  uA2 = pkfma(w2[4], sp(m4), uA2);       \
        uB1 = pkfma(w1[5], sp(m5), uB1);  uB2 = pkfma(w2[5], sp(m5), uB2);       \
        uA1 = pkfma(w1[6], sp(m6), uA1);  uA2 = pkfma(w2[6], sp(m6), uA2);       \
        uB1 = pkfma(w1[7], sp(m7), uB1);  uB2 = pkfma(w2[7], sp(m7), uB2);       \
        v2f u1 = uA1 + uB1;    /* (u_i, u_f) sigma-prescaled */                  \
        v2f u2 = uA2 + uB2;    /* (u_g raw, u_o sigma-prescaled) */              \
        XG = *(const float4*)(TABj + (NIDX) * TABSTRIDE);   /* prefetch t+2 */   \
        float ei = __builtin_amdgcn_exp2f(u1.x);                                 \
        float ef = __builtin_amdgcn_exp2f(u1.y);                                 \
        float eo = __builtin_amdgcn_exp2f(u2.y);                                 \
        float si = __builtin_amdgcn_rcpf(1.0f + ei);                             \
        float sf = __builtin_amdgcn_rcpf(1.0f + ef);                             \
        float so = __builtin_amdgcn_rcpf(1.0f + eo);                             \
        float tg = tanh_f32(u2.x);                                               \
        c  = __builtin_fmaf(sf, c, si * tg);                                     \
        hn = so * tanh_f32(c);                                                   \
    } while (0)

    for (int t = 0; t < TT; t += 4) {
        const int nb = (t + 8 < TT) ? (t / 4 + 2) : 0;  // clamp tail prefetch
        int4 iN = *(const int4*)(xrow + nb * 4);
        STEP(xg0, iA.z);
        STEP(xg1, iA.w);
        STEP(xg0, iB.x);
        STEP(xg1, iB.y);
        iA = iB; iB = iN;
    }
#undef STEP

    // ---- head: out[b] = 0.5 + 0.5*tanh(0.5*(h.W_cls + b_cls)) ----
    // Lane j==0: hn=h_0, m1..m7 = h_1..h_7 -> same summation order as R2-R7.
    {
        float m1 = dppf<DPP_XOR1>(hn);
        float m2 = dppf<DPP_XOR2>(hn);
        float m3 = dppf<DPP_XOR3>(hn);
        float m7 = dppf<DPP_HMIR>(hn);
        float m6 = dppf<DPP_XOR1>(m7);
        float m5 = dppf<DPP_XOR2>(m7);
        float m4 = dppf<DPP_XOR3>(m7);
        if (j == 0) {
            float z = b_cls[0]
                + hn * W_cls[0] + m1 * W_cls[1] + m2 * W_cls[2] + m3 * W_cls[3]
                + m4 * W_cls[4] + m5 * W_cls[5] + m6 * W_cls[6] + m7 * W_cls[7];
            out[b] = __builtin_fmaf(0.5f, tanh_f32(0.5f * z), 0.5f);
        }
    }
}

extern "C" void kernel_launch(void* const* d_in, const int* in_sizes, int n_in,
                              void* d_out, int out_size, void* d_ws, size_t ws_size,
                              hipStream_t stream)
{
    (void)in_sizes; (void)n_in; (void)d_ws; (void)ws_size; (void)out_size;
    const int*   x     = (const int*)  d_in[0];
    const float* emb   = (const float*)d_in[1];
    const float* W_ih  = (const float*)d_in[2];
    const float* W_hh  = (const float*)d_in[3];
    const float* b_ih  = (const float*)d_in[4];
    const float* b_hh  = (const float*)d_in[5];
    const float* W_cls = (const float*)d_in[6];
    const float* b_cls = (const float*)d_in[7];
    float* out = (float*)d_out;

    const int lds_bytes = NV * TABSTRIDE;  // 160000 <= 163840 (gfx950 opt-in)
    hipFuncSetAttribute((const void*)lstm_fused,
                        hipFuncAttributeMaxDynamicSharedMemorySize, lds_bytes);

    lstm_fused<<<dim3(256), dim3(256), lds_bytes, stream>>>(
        x, emb, W_ih, W_hh, b_ih, b_hh, W_cls, b_cls, out);
}

// Round 9
// 367.159 us; speedup vs baseline: 1.1607x; 1.0932x over previous
//
#include <hip/hip_runtime.h>

#define TT 2048
#define NV 1000
#define LOG2E 1.4426950408889634f

// ---- XLA/Eigen f32 tanh, scalar, op-sequence VERBATIM from R2-R8 passes ----
// (med3 clamp == min(max()) bitwise for non-NaN). g-gate and cell tanh only.
__device__ __forceinline__ float tanh_f32(float x) {
    const float L = 7.90531110763549805f;
    x = __builtin_amdgcn_fmed3f(x, -L, L);
    float x2 = x * x;
    float p = -2.76076847742355e-16f;
    p = __builtin_fmaf(p, x2, 2.00018790482477e-13f);
    p = __builtin_fmaf(p, x2, -8.60467152213735e-11f);
    p = __builtin_fmaf(p, x2, 5.12229709037114e-08f);
    p = __builtin_fmaf(p, x2, 1.48572235717979e-05f);
    p = __builtin_fmaf(p, x2, 6.37261928875436e-04f);
    p = __builtin_fmaf(p, x2, 4.89352455891786e-03f);
    float q = 1.19825839466702e-06f;
    q = __builtin_fmaf(q, x2, 1.18534705686654e-04f);
    q = __builtin_fmaf(q, x2, 2.26843463243900e-03f);
    q = __builtin_fmaf(q, x2, 4.89352518554385e-03f);
    float r = __builtin_amdgcn_rcpf(q);
    r = __builtin_fmaf(__builtin_fmaf(-q, r, 1.0f), r, r);  // Newton: <=1 ulp
    return (x * p) * r;
}

// DPP cross-lane. Each dppf call below is written SINGLE-USE at its consumer
// so GCNDPPCombine can fold the v_mov_dpp into VOP2 v_fmac/v_mul (free DPP).
template <int CTRL>
__device__ __forceinline__ float dppf(float x) {
    return __int_as_float(__builtin_amdgcn_update_dpp(
        0, __float_as_int(x), CTRL, 0xF, 0xF, true));
}
#define DPP_XOR1 0xB1   // quad_perm [1,0,3,2]
#define DPP_XOR2 0x4E   // quad_perm [2,3,0,1]
#define DPP_XOR3 0x1B   // quad_perm [3,2,1,0]
#define DPP_ROR4 0x124  // row_ror:4 == xor4 on period-8 data (validated R3-R6)
#define DPP_HMIR 0x141  // row_half_mirror == xor7 within 8-lane half
#define DPP_ROR8 0x128  // row_ror:8 == xor8 within 16-row

// R6 structure (best: 373 us), de-packed: 16 lanes/row, lane l = s*8+j;
//   s=0 -> gates (i_j, f_j) [both sigma]; s=1 -> (g_j, o_j) [tanh, sigma].
// sigma(x) = rcp(1+exp2(-log2e*x)) (R6-validated, absmax 0.0); g/c rational
// tanh. Dot = 4 scalar fmac chains (lo/hi x even/odd), DPP folded into fmac.
// Per-component op order IDENTICAL to R6. 65536 thr = 1024 waves = 1/SIMD.
extern "C" __global__ void __launch_bounds__(256, 1)
lstm_fused(const int* __restrict__ x, const float* __restrict__ emb,
           const float* __restrict__ W_ih, const float* __restrict__ W_hh,
           const float* __restrict__ b_ih, const float* __restrict__ b_hh,
           const float* __restrict__ W_cls, const float* __restrict__ b_cls,
           float* __restrict__ out)
{
    extern __shared__ float TAB[];  // [1000][16] float2 rows, stride 128 B

    const int tid = threadIdx.x;
    const int l   = tid & 15;
    const int s   = l >> 3;
    const int j   = l & 7;
    const int grp = tid >> 4;

    const int glo = j + (s << 4);          // i_j (s0) or g_j (s1)
    const int ghi = glo + 8;               // f_j (s0) or o_j (s1)
    const float scx = s ? 1.0f : -LOG2E;   // g-slot raw; sigma-slots -log2e
    const float scy = -LOG2E;
    const bool is0 = (s == 0);
    const bool is1 = !is0;

    // ---- phase 1: build TAB (identical to R6) ----
    {
        float wl[8], wh[8];
        #pragma unroll
        for (int k = 0; k < 8; ++k) {
            wl[k] = W_ih[glo * 8 + k];
            wh[k] = W_ih[ghi * 8 + k];
        }
        const float bl = b_ih[glo] + b_hh[glo];
        const float bh = b_ih[ghi] + b_hh[ghi];
        for (int v = grp; v < NV; v += 16) {
            const float4 e0 = *(const float4*)(emb + v * 8);
            const float4 e1 = *(const float4*)(emb + v * 8 + 4);
            float dl = bl + e0.x*wl[0] + e0.y*wl[1] + e0.z*wl[2] + e0.w*wl[3]
                          + e1.x*wl[4] + e1.y*wl[5] + e1.z*wl[6] + e1.w*wl[7];
            float dh = bh + e0.x*wh[0] + e0.y*wh[1] + e0.z*wh[2] + e0.w*wh[3]
                          + e1.x*wh[4] + e1.y*wh[5] + e1.z*wh[6] + e1.w*wh[7];
            *(float2*)(TAB + v * 32 + l * 2) = make_float2(scx * dl, scy * dh);
        }
    }
    __syncthreads();

    // ---- recurrence ----
    const int b = blockIdx.x * 16 + grp;
    const int* __restrict__ xrow = x + (size_t)b * TT;
    const char* __restrict__ TABl = (const char*)TAB + l * 8;  // lane base

    // xor-ordered W_hh (pairs with m_k = h_{j^m}; validated R3-R8 absmax 0.0)
    float wlo[8], whi[8];
    #pragma unroll
    for (int m = 0; m < 8; ++m) {
        wlo[m] = scx * W_hh[glo * 8 + (j ^ m)];
        whi[m] = scy * W_hh[ghi * 8 + (j ^ m)];
    }

    float c  = 0.0f;
    float hn = 0.0f;   // lane l: h_{l&7} (period-8 within 16-row)

    int4 iA = *(const int4*)(xrow);
    int4 iB = *(const int4*)(xrow + 4);
    float2 xg0 = *(const float2*)(TABl + (iA.x << 7));  // depth-2 prefetch
    float2 xg1 = *(const float2*)(TABl + (iA.y << 7));

    // Chain order per component == R6: uA: m0,m2,m4,m6; uB: m1,m3,m5,m7; u=uA+uB.
    // m7=HMIR(hn) materialized once (multi-use); all other DPPs single-use ->
    // fold into v_fmac/v_mul.
#define STEP(XG, NIDX) do {                                                      \
        float mm  = dppf<DPP_HMIR>(hn);          /* m7, multi-use */             \
        float uAl = __builtin_fmaf(wlo[0], hn, XG.x);                            \
        float uAh = __builtin_fmaf(whi[0], hn, XG.y);                            \
        float uBl = dppf<DPP_XOR1>(hn) * wlo[1];                                 \
        float uBh = dppf<DPP_XOR1>(hn) * whi[1];                                 \
        uAl = __builtin_fmaf(dppf<DPP_XOR2>(hn), wlo[2], uAl);                   \
        uAh = __builtin_fmaf(dppf<DPP_XOR2>(hn), whi[2], uAh);                   \
        uBl = __builtin_fmaf(dppf<DPP_XOR3>(hn), wlo[3], uBl);                   \
        uBh = __builtin_fmaf(dppf<DPP_XOR3>(hn), whi[3], uBh);                   \
        uAl = __builtin_fmaf(dppf<DPP_XOR3>(mm), wlo[4], uAl);                   \
        uAh = __builtin_fmaf(dppf<DPP_XOR3>(mm), whi[4], uAh);                   \
        uBl = __builtin_fmaf(dppf<DPP_XOR2>(mm), wlo[5], uBl);                   \
        uBh = __builtin_fmaf(dppf<DPP_XOR2>(mm), whi[5], uBh);                   \
        uAl = __builtin_fmaf(dppf<DPP_XOR1>(mm), wlo[6], uAl);                   \
        uAh = __builtin_fmaf(dppf<DPP_XOR1>(mm), whi[6], uAh);                   \
        uBl = __builtin_fmaf(mm, wlo[7], uBl);                                   \
        uBh = __builtin_fmaf(mm, whi[7], uBh);                                   \
        float ul = uAl + uBl;   /* s0: -log2e*pre_i ; s1: raw pre_g */           \
        float uh = uAh + uBh;   /* s0: -log2e*pre_f ; s1: -log2e*pre_o */        \
        XG = *(const float2*)(TABl + ((NIDX) << 7));   /* prefetch t+2 */        \
        float ex = __builtin_amdgcn_exp2f(ul);                                   \
        float ey = __builtin_amdgcn_exp2f(uh);                                   \
        float sx = __builtin_amdgcn_rcpf(1.0f + ex);                             \
        float sy = __builtin_amdgcn_rcpf(1.0f + ey);                             \
        float tg = tanh_f32(ul);        /* s1: tanh(g); s0 discarded */          \
        float ax = is1 ? tg : sx;       /* s0: sig(i);  s1: tanh(g) */           \
        float ay = sy;                  /* s0: sig(f);  s1: sig(o)  */           \
        float IG  = dppf<DPP_ROR8>(ax) * ax;    /* sig(i)*tanh(g), both */       \
        float pHi = dppf<DPP_ROR8>(ay);                                          \
        float F   = is0 ? ay : pHi;     /* sig(f) */                             \
        float O   = is0 ? pHi : ay;     /* sig(o) */                             \
        c  = __builtin_fmaf(F, c, IG);                                           \
        hn = O * tanh_f32(c);                                                    \
    } while (0)

    for (int t = 0; t < TT; t += 4) {
        const int nb = (t + 8 < TT) ? (t / 4 + 2) : 0;  // clamp tail prefetch
        int4 iN = *(const int4*)(xrow + nb * 4);
        STEP(xg0, iA.z);
        STEP(xg1, iA.w);
        STEP(xg0, iB.x);
        STEP(xg1, iB.y);
        iA = iB; iB = iN;
    }
#undef STEP

    // ---- head: out[b] = 0.5 + 0.5*tanh(0.5*(h.W_cls + b_cls)) ----
    // Lane l==0: hn=h_0, v_m=h_m -> same summation order as R2-R8.
    {
        float v1 = dppf<DPP_XOR1>(hn);
        float v2 = dppf<DPP_XOR2>(hn);
        float v3 = dppf<DPP_XOR3>(hn);
        float v4 = dppf<DPP_ROR4>(hn);
        float v5 = dppf<DPP_XOR1>(v4);
        float v6 = dppf<DPP_XOR2>(v4);
        float v7 = dppf<DPP_XOR3>(v4);
        if (l == 0) {
            float z = b_cls[0]
                + hn * W_cls[0] + v1 * W_cls[1] + v2 * W_cls[2] + v3 * W_cls[3]
                + v4 * W_cls[4] + v5 * W_cls[5] + v6 * W_cls[6] + v7 * W_cls[7];
            out[b] = __builtin_fmaf(0.5f, tanh_f32(0.5f * z), 0.5f);
        }
    }
}

extern "C" void kernel_launch(void* const* d_in, const int* in_sizes, int n_in,
                              void* d_out, int out_size, void* d_ws, size_t ws_size,
                              hipStream_t stream)
{
    (void)in_sizes; (void)n_in; (void)d_ws; (void)ws_size; (void)out_size;
    const int*   x     = (const int*)  d_in[0];
    const float* emb   = (const float*)d_in[1];
    const float* W_ih  = (const float*)d_in[2];
    const float* W_hh  = (const float*)d_in[3];
    const float* b_ih  = (const float*)d_in[4];
    const float* b_hh  = (const float*)d_in[5];
    const float* W_cls = (const float*)d_in[6];
    const float* b_cls = (const float*)d_in[7];
    float* out = (float*)d_out;

    const int lds_bytes = NV * 16 * 8;  // 128000 <= 163840 (gfx950 opt-in)
    hipFuncSetAttribute((const void*)lstm_fused,
                        hipFuncAttributeMaxDynamicSharedMemorySize, lds_bytes);

    lstm_fused<<<dim3(256), dim3(256), lds_bytes, stream>>>(
        x, emb, W_ih, W_hh, b_ih, b_hh, W_cls, b_cls, out);
}

// Round 10
// 334.284 us; speedup vs baseline: 1.2748x; 1.0983x over previous
//
#include <hip/hip_runtime.h>

#define TT 2048
#define NV 1000
#define LOG2E 1.4426950408889634f

// ---- XLA/Eigen rational tanh, MINUS the rcp Newton step (R10's single new
// numerics variable). Raw v_rcp is <=1 ulp RELATIVE, non-cancelling — same
// error class as the exp2-sigma path validated absmax 0.0 in R6-R9. The
// polynomial + clamp + op order stay verbatim from the R2-R9 passes.
__device__ __forceinline__ float tanh_fast(float x) {
    const float L = 7.90531110763549805f;
    x = __builtin_amdgcn_fmed3f(x, -L, L);
    float x2 = x * x;
    float p = -2.76076847742355e-16f;
    p = __builtin_fmaf(p, x2, 2.00018790482477e-13f);
    p = __builtin_fmaf(p, x2, -8.60467152213735e-11f);
    p = __builtin_fmaf(p, x2, 5.12229709037114e-08f);
    p = __builtin_fmaf(p, x2, 1.48572235717979e-05f);
    p = __builtin_fmaf(p, x2, 6.37261928875436e-04f);
    p = __builtin_fmaf(p, x2, 4.89352455891786e-03f);
    float q = 1.19825839466702e-06f;
    q = __builtin_fmaf(q, x2, 1.18534705686654e-04f);
    q = __builtin_fmaf(q, x2, 2.26843463243900e-03f);
    q = __builtin_fmaf(q, x2, 4.89352518554385e-03f);
    float r = __builtin_amdgcn_rcpf(q);   // no Newton (see header note)
    return (x * p) * r;
}

// DPP cross-lane; single-use at consumers where possible.
template <int CTRL>
__device__ __forceinline__ float dppf(float x) {
    return __int_as_float(__builtin_amdgcn_update_dpp(
        0, __float_as_int(x), CTRL, 0xF, 0xF, true));
}
#define DPP_XOR1 0xB1   // quad_perm [1,0,3,2]
#define DPP_XOR2 0x4E   // quad_perm [2,3,0,1]
#define DPP_XOR3 0x1B   // quad_perm [3,2,1,0]
#define DPP_ROR4 0x124  // row_ror:4 == xor4 on period-8 data (validated R3-R9)
#define DPP_HMIR 0x141  // row_half_mirror == xor7 within 8-lane half
#define DPP_ROR8 0x128  // row_ror:8 == xor8 within 16-row

// 16 lanes/row (forced by R7/R8 facts), lane l = s*8+j.
//   lo slot: s=0 -> i_j (sigma via 0.5+0.5*tanh(pre/2), prescale 0.5 — the
//            R2-validated form), s=1 -> g_j (tanh, prescale 1.0).
//   ONE rational tanh serves both lo slots (no duplicated exp-sigma).
//   hi slot: s=0 -> f_j, s=1 -> o_j, both sigma via rcp(1+exp2(-log2e*pre))
//            (R6-validated). Trans ops per step: 4 (was 6).
extern "C" __global__ void __launch_bounds__(256, 1)
lstm_fused(const int* __restrict__ x, const float* __restrict__ emb,
           const float* __restrict__ W_ih, const float* __restrict__ W_hh,
           const float* __restrict__ b_ih, const float* __restrict__ b_hh,
           const float* __restrict__ W_cls, const float* __restrict__ b_cls,
           float* __restrict__ out)
{
    extern __shared__ float TAB[];  // [1000][16] float2 rows, stride 128 B

    const int tid = threadIdx.x;
    const int l   = tid & 15;
    const int s   = l >> 3;
    const int j   = l & 7;
    const int grp = tid >> 4;

    const int glo = j + (s << 4);          // i_j (s0) or g_j (s1)
    const int ghi = glo + 8;               // f_j (s0) or o_j (s1)
    const float scx = s ? 1.0f : 0.5f;     // lo-slot prescale (exact pow2 on s0)
    const float scy = -LOG2E;              // hi-slot sigma prescale
    const float saL = s ? 1.0f : 0.5f;     // act_lo = saL*T + sbL
    const float sbL = s ? 0.0f : 0.5f;
    const bool is0 = (s == 0);

    // ---- phase 1: build TAB ----
    {
        float wl[8], wh[8];
        #pragma unroll
        for (int k = 0; k < 8; ++k) {
            wl[k] = W_ih[glo * 8 + k];
            wh[k] = W_ih[ghi * 8 + k];
        }
        const float bl = b_ih[glo] + b_hh[glo];
        const float bh = b_ih[ghi] + b_hh[ghi];
        for (int v = grp; v < NV; v += 16) {
            const float4 e0 = *(const float4*)(emb + v * 8);
            const float4 e1 = *(const float4*)(emb + v * 8 + 4);
            float dl = bl + e0.x*wl[0] + e0.y*wl[1] + e0.z*wl[2] + e0.w*wl[3]
                          + e1.x*wl[4] + e1.y*wl[5] + e1.z*wl[6] + e1.w*wl[7];
            float dh = bh + e0.x*wh[0] + e0.y*wh[1] + e0.z*wh[2] + e0.w*wh[3]
                          + e1.x*wh[4] + e1.y*wh[5] + e1.z*wh[6] + e1.w*wh[7];
            *(float2*)(TAB + v * 32 + l * 2) = make_float2(scx * dl, scy * dh);
        }
    }
    __syncthreads();

    // ---- recurrence ----
    const int b = blockIdx.x * 16 + grp;
    const int* __restrict__ xrow = x + (size_t)b * TT;
    const char* __restrict__ TABl = (const char*)TAB + l * 8;  // lane base

    // xor-ordered W_hh (pairs with m_k = h_{j^m}; validated R3-R9 absmax 0.0)
    float wlo[8], whi[8];
    #pragma unroll
    for (int m = 0; m < 8; ++m) {
        wlo[m] = scx * W_hh[glo * 8 + (j ^ m)];
        whi[m] = scy * W_hh[ghi * 8 + (j ^ m)];
    }

    float c  = 0.0f;
    float hn = 0.0f;   // lane l: h_{l&7} (period-8 within 16-row)

    int4 iA = *(const int4*)(xrow);
    int4 iB = *(const int4*)(xrow + 4);
    float2 xg0 = *(const float2*)(TABl + (iA.x << 7));  // depth-2 prefetch
    float2 xg1 = *(const float2*)(TABl + (iA.y << 7));

    // Dot chain order per component == R6/R9: uA: m0,m2,m4,m6; uB: m1,m3,m5,m7.
#define STEP(XG, NIDX) do {                                                      \
        float mm  = dppf<DPP_HMIR>(hn);          /* m7, multi-use */             \
        float uAl = __builtin_fmaf(wlo[0], hn, XG.x);                            \
        float uAh = __builtin_fmaf(whi[0], hn, XG.y);                            \
        float uBl = dppf<DPP_XOR1>(hn) * wlo[1];                                 \
        float uBh = dppf<DPP_XOR1>(hn) * whi[1];                                 \
        uAl = __builtin_fmaf(dppf<DPP_XOR2>(hn), wlo[2], uAl);                   \
        uAh = __builtin_fmaf(dppf<DPP_XOR2>(hn), whi[2], uAh);                   \
        uBl = __builtin_fmaf(dppf<DPP_XOR3>(hn), wlo[3], uBl);                   \
        uBh = __builtin_fmaf(dppf<DPP_XOR3>(hn), whi[3], uBh);                   \
        uAl = __builtin_fmaf(dppf<DPP_XOR3>(mm), wlo[4], uAl);                   \
        uAh = __builtin_fmaf(dppf<DPP_XOR3>(mm), whi[4], uAh);                   \
        uBl = __builtin_fmaf(dppf<DPP_XOR2>(mm), wlo[5], uBl);                   \
        uBh = __builtin_fmaf(dppf<DPP_XOR2>(mm), whi[5], uBh);                   \
        uAl = __builtin_fmaf(dppf<DPP_XOR1>(mm), wlo[6], uAl);                   \
        uAh = __builtin_fmaf(dppf<DPP_XOR1>(mm), whi[6], uAh);                   \
        uBl = __builtin_fmaf(mm, wlo[7], uBl);                                   \
        uBh = __builtin_fmaf(mm, whi[7], uBh);                                   \
        float ul = uAl + uBl;   /* s0: 0.5*pre_i ; s1: raw pre_g */              \
        float uh = uAh + uBh;   /* s0/s1: -log2e*pre_{f,o} */                    \
        XG = *(const float2*)(TABl + ((NIDX) << 7));   /* prefetch t+2 */        \
        float ey = __builtin_amdgcn_exp2f(uh);                                   \
        float sy = __builtin_amdgcn_rcpf(1.0f + ey);   /* sig(f) or sig(o) */    \
        float T1 = tanh_fast(ul);                                                \
        float aL = __builtin_fmaf(saL, T1, sbL);  /* s0: sig(i); s1: tanh(g) */  \
        float IG  = dppf<DPP_ROR8>(aL) * aL;      /* sig(i)*tanh(g), both */     \
        float pHi = dppf<DPP_ROR8>(sy);                                          \
        float F   = is0 ? sy : pHi;     /* sig(f) */                             \
        float O   = is0 ? pHi : sy;     /* sig(o) */                             \
        c  = __builtin_fmaf(F, c, IG);                                           \
        hn = O * tanh_fast(c);                                                   \
    } while (0)

    for (int t = 0; t < TT; t += 4) {
        const int nb = (t + 8 < TT) ? (t / 4 + 2) : 0;  // clamp tail prefetch
        int4 iN = *(const int4*)(xrow + nb * 4);
        STEP(xg0, iA.z);
        STEP(xg1, iA.w);
        STEP(xg0, iB.x);
        STEP(xg1, iB.y);
        iA = iB; iB = iN;
    }
#undef STEP

    // ---- head: out[b] = 0.5 + 0.5*tanh(0.5*(h.W_cls + b_cls)) ----
    // Lane l==0: hn=h_0, v_m=h_m -> same summation order as R2-R9.
    {
        float v1 = dppf<DPP_XOR1>(hn);
        float v2 = dppf<DPP_XOR2>(hn);
        float v3 = dppf<DPP_XOR3>(hn);
        float v4 = dppf<DPP_ROR4>(hn);
        float v5 = dppf<DPP_XOR1>(v4);
        float v6 = dppf<DPP_XOR2>(v4);
        float v7 = dppf<DPP_XOR3>(v4);
        if (l == 0) {
            float z = b_cls[0]
                + hn * W_cls[0] + v1 * W_cls[1] + v2 * W_cls[2] + v3 * W_cls[3]
                + v4 * W_cls[4] + v5 * W_cls[5] + v6 * W_cls[6] + v7 * W_cls[7];
            out[b] = __builtin_fmaf(0.5f, tanh_fast(0.5f * z), 0.5f);
        }
    }
}

extern "C" void kernel_launch(void* const* d_in, const int* in_sizes, int n_in,
                              void* d_out, int out_size, void* d_ws, size_t ws_size,
                              hipStream_t stream)
{
    (void)in_sizes; (void)n_in; (void)d_ws; (void)ws_size; (void)out_size;
    const int*   x     = (const int*)  d_in[0];
    const float* emb   = (const float*)d_in[1];
    const float* W_ih  = (const float*)d_in[2];
    const float* W_hh  = (const float*)d_in[3];
    const float* b_ih  = (const float*)d_in[4];
    const float* b_hh  = (const float*)d_in[5];
    const float* W_cls = (const float*)d_in[6];
    const float* b_cls = (const float*)d_in[7];
    float* out = (float*)d_out;

    const int lds_bytes = NV * 16 * 8;  // 128000 <= 163840 (gfx950 opt-in)
    hipFuncSetAttribute((const void*)lstm_fused,
                        hipFuncAttributeMaxDynamicSharedMemorySize, lds_bytes);

    lstm_fused<<<dim3(256), dim3(256), lds_bytes, stream>>>(
        x, emb, W_ih, W_hh, b_ih, b_hh, W_cls, b_cls, out);
}

// Round 11
// 298.221 us; speedup vs baseline: 1.4290x; 1.1209x over previous
//
#include <hip/hip_runtime.h>

#define TT 2048
#define NV 1000
#define LOG2E 1.4426950408889634f

// ---- XLA/Eigen rational tanh (R2-lineage). Now used ONLY in the epilogue
// head (off the critical path). The recurrence uses exp-form tanh (below).
__device__ __forceinline__ float tanh_fast(float x) {
    const float L = 7.90531110763549805f;
    x = __builtin_amdgcn_fmed3f(x, -L, L);
    float x2 = x * x;
    float p = -2.76076847742355e-16f;
    p = __builtin_fmaf(p, x2, 2.00018790482477e-13f);
    p = __builtin_fmaf(p, x2, -8.60467152213735e-11f);
    p = __builtin_fmaf(p, x2, 5.12229709037114e-08f);
    p = __builtin_fmaf(p, x2, 1.48572235717979e-05f);
    p = __builtin_fmaf(p, x2, 6.37261928875436e-04f);
    p = __builtin_fmaf(p, x2, 4.89352455891786e-03f);
    float q = 1.19825839466702e-06f;
    q = __builtin_fmaf(q, x2, 1.18534705686654e-04f);
    q = __builtin_fmaf(q, x2, 2.26843463243900e-03f);
    q = __builtin_fmaf(q, x2, 4.89352518554385e-03f);
    float r = __builtin_amdgcn_rcpf(q);
    return (x * p) * r;
}

// DPP cross-lane; single-use at consumers where possible.
template <int CTRL>
__device__ __forceinline__ float dppf(float x) {
    return __int_as_float(__builtin_amdgcn_update_dpp(
        0, __float_as_int(x), CTRL, 0xF, 0xF, true));
}
#define DPP_XOR1 0xB1   // quad_perm [1,0,3,2]
#define DPP_XOR2 0x4E   // quad_perm [2,3,0,1]
#define DPP_XOR3 0x1B   // quad_perm [3,2,1,0]
#define DPP_ROR4 0x124  // row_ror:4 == xor4 on period-8 data (validated R3-R10)
#define DPP_HMIR 0x141  // row_half_mirror == xor7 within 8-lane half
#define DPP_ROR8 0x128  // row_ror:8 == xor8 within 16-row

// 16 lanes/row (forced by R7/R8 occupancy facts), lane l = s*8+j.
// R11 EXPERIMENT (single variable): exp-form tanh for g and tanh(c):
//   tanh(x) = (1-e)*rcp(1+e), e = exp2(-2*log2e*x).
// Sterbenz: 1-e exact for e in [0.5,2] -> injected error = exp2's ~1 ulp of
// e (~6e-8 abs) == the exp-sigma error class validated absmax 0.0 in R6-R10.
// If this FAILS (~1e-2), exp-tanh is indicted (consistent w/ R1) -> revert.
//   lo slot: s=0 -> i (sigma, e-form, prescale -log2e; n=1)
//            s=1 -> g (tanh, e-form, prescale -2log2e; n=1-e)
//   hi slot: f/o sigma via rcp(1+exp2(-log2e*pre)) (R6-validated, unchanged).
// Trans/step: 3 exp + 3 rcp; poly fmas gone (-17 instr vs R10).
extern "C" __global__ void __launch_bounds__(256, 1)
lstm_fused(const int* __restrict__ x, const float* __restrict__ emb,
           const float* __restrict__ W_ih, const float* __restrict__ W_hh,
           const float* __restrict__ b_ih, const float* __restrict__ b_hh,
           const float* __restrict__ W_cls, const float* __restrict__ b_cls,
           float* __restrict__ out)
{
    extern __shared__ float TAB[];  // [1000][16] float2 rows, stride 128 B

    const int tid = threadIdx.x;
    const int l   = tid & 15;
    const int s   = l >> 3;
    const int j   = l & 7;
    const int grp = tid >> 4;

    const int glo = j + (s << 4);          // i_j (s0) or g_j (s1)
    const int ghi = glo + 8;               // f_j (s0) or o_j (s1)
    const float scx = s ? (-2.0f * LOG2E) : -LOG2E;  // lo-slot prescale
    const float scy = -LOG2E;                        // hi-slot sigma prescale
    const float kL  = s ? 1.0f : 0.0f;     // lo numerator: n = 1 - kL*e
    const bool is0 = (s == 0);

    // ---- phase 1: build TAB ----
    {
        float wl[8], wh[8];
        #pragma unroll
        for (int k = 0; k < 8; ++k) {
            wl[k] = W_ih[glo * 8 + k];
            wh[k] = W_ih[ghi * 8 + k];
        }
        const float bl = b_ih[glo] + b_hh[glo];
        const float bh = b_ih[ghi] + b_hh[ghi];
        for (int v = grp; v < NV; v += 16) {
            const float4 e0 = *(const float4*)(emb + v * 8);
            const float4 e1 = *(const float4*)(emb + v * 8 + 4);
            float dl = bl + e0.x*wl[0] + e0.y*wl[1] + e0.z*wl[2] + e0.w*wl[3]
                          + e1.x*wl[4] + e1.y*wl[5] + e1.z*wl[6] + e1.w*wl[7];
            float dh = bh + e0.x*wh[0] + e0.y*wh[1] + e0.z*wh[2] + e0.w*wh[3]
                          + e1.x*wh[4] + e1.y*wh[5] + e1.z*wh[6] + e1.w*wh[7];
            *(float2*)(TAB + v * 32 + l * 2) = make_float2(scx * dl, scy * dh);
        }
    }
    __syncthreads();

    // ---- recurrence ----
    const int b = blockIdx.x * 16 + grp;
    const int* __restrict__ xrow = x + (size_t)b * TT;
    const char* __restrict__ TABl = (const char*)TAB + l * 8;  // lane base

    // xor-ordered W_hh (pairs with m_k = h_{j^m}; validated R3-R10 absmax 0.0)
    float wlo[8], whi[8];
    #pragma unroll
    for (int m = 0; m < 8; ++m) {
        wlo[m] = scx * W_hh[glo * 8 + (j ^ m)];
        whi[m] = scy * W_hh[ghi * 8 + (j ^ m)];
    }

    float c  = 0.0f;
    float hn = 0.0f;   // lane l: h_{l&7} (period-8 within 16-row)

    int4 iA = *(const int4*)(xrow);
    int4 iB = *(const int4*)(xrow + 4);
    float2 xg0 = *(const float2*)(TABl + (iA.x << 7));  // depth-2 prefetch
    float2 xg1 = *(const float2*)(TABl + (iA.y << 7));

    // Dot chain order per component == R6/R9/R10: uA: m0,m2,m4,m6; uB: m1,m3,m5,m7.
#define STEP(XG, NIDX) do {                                                      \
        float mm  = dppf<DPP_HMIR>(hn);          /* m7, multi-use */             \
        float uAl = __builtin_fmaf(wlo[0], hn, XG.x);                            \
        float uAh = __builtin_fmaf(whi[0], hn, XG.y);                            \
        float uBl = dppf<DPP_XOR1>(hn) * wlo[1];                                 \
        float uBh = dppf<DPP_XOR1>(hn) * whi[1];                                 \
        uAl = __builtin_fmaf(dppf<DPP_XOR2>(hn), wlo[2], uAl);                   \
        uAh = __builtin_fmaf(dppf<DPP_XOR2>(hn), whi[2], uAh);                   \
        uBl = __builtin_fmaf(dppf<DPP_XOR3>(hn), wlo[3], uBl);                   \
        uBh = __builtin_fmaf(dppf<DPP_XOR3>(hn), whi[3], uBh);                   \
        uAl = __builtin_fmaf(dppf<DPP_XOR3>(mm), wlo[4], uAl);                   \
        uAh = __builtin_fmaf(dppf<DPP_XOR3>(mm), whi[4], uAh);                   \
        uBl = __builtin_fmaf(dppf<DPP_XOR2>(mm), wlo[5], uBl);                   \
        uBh = __builtin_fmaf(dppf<DPP_XOR2>(mm), whi[5], uBh);                   \
        uAl = __builtin_fmaf(dppf<DPP_XOR1>(mm), wlo[6], uAl);                   \
        uAh = __builtin_fmaf(dppf<DPP_XOR1>(mm), whi[6], uAh);                   \
        uBl = __builtin_fmaf(mm, wlo[7], uBl);                                   \
        uBh = __builtin_fmaf(mm, whi[7], uBh);                                   \
        float ul = uAl + uBl;   /* s0: -log2e*pre_i ; s1: -2log2e*pre_g */       \
        float uh = uAh + uBh;   /* s0/s1: -log2e*pre_{f,o} */                    \
        XG = *(const float2*)(TABl + ((NIDX) << 7));   /* prefetch t+2 */        \
        float el = __builtin_amdgcn_exp2f(fminf(ul, 126.0f));                    \
        float ey = __builtin_amdgcn_exp2f(uh);                                   \
        float nl = __builtin_fmaf(-kL, el, 1.0f);  /* s0: 1; s1: 1-el */         \
        float aL = nl * __builtin_amdgcn_rcpf(1.0f + el);  /* sig(i)/tanh(g) */  \
        float sy = __builtin_amdgcn_rcpf(1.0f + ey);       /* sig(f)/sig(o) */   \
        float IG  = dppf<DPP_ROR8>(aL) * aL;      /* sig(i)*tanh(g), both */     \
        float pHi = dppf<DPP_ROR8>(sy);                                          \
        float F   = is0 ? sy : pHi;     /* sig(f) */                             \
        float O   = is0 ? pHi : sy;     /* sig(o) */                             \
        c  = __builtin_fmaf(F, c, IG);                                           \
        float uc = fminf(c * (-2.0f * LOG2E), 126.0f);                           \
        float ec = __builtin_amdgcn_exp2f(uc);                                   \
        float tc = (1.0f - ec) * __builtin_amdgcn_rcpf(1.0f + ec);               \
        hn = O * tc;                                                             \
    } while (0)

    for (int t = 0; t < TT; t += 4) {
        const int nb = (t + 8 < TT) ? (t / 4 + 2) : 0;  // clamp tail prefetch
        int4 iN = *(const int4*)(xrow + nb * 4);
        STEP(xg0, iA.z);
        STEP(xg1, iA.w);
        STEP(xg0, iB.x);
        STEP(xg1, iB.y);
        iA = iB; iB = iN;
    }
#undef STEP

    // ---- head: out[b] = 0.5 + 0.5*tanh(0.5*(h.W_cls + b_cls)) ----
    // Lane l==0: hn=h_0, v_m=h_m -> same summation order as R2-R10.
    {
        float v1 = dppf<DPP_XOR1>(hn);
        float v2 = dppf<DPP_XOR2>(hn);
        float v3 = dppf<DPP_XOR3>(hn);
        float v4 = dppf<DPP_ROR4>(hn);
        float v5 = dppf<DPP_XOR1>(v4);
        float v6 = dppf<DPP_XOR2>(v4);
        float v7 = dppf<DPP_XOR3>(v4);
        if (l == 0) {
            float z = b_cls[0]
                + hn * W_cls[0] + v1 * W_cls[1] + v2 * W_cls[2] + v3 * W_cls[3]
                + v4 * W_cls[4] + v5 * W_cls[5] + v6 * W_cls[6] + v7 * W_cls[7];
            out[b] = __builtin_fmaf(0.5f, tanh_fast(0.5f * z), 0.5f);
        }
    }
}

extern "C" void kernel_launch(void* const* d_in, const int* in_sizes, int n_in,
                              void* d_out, int out_size, void* d_ws, size_t ws_size,
                              hipStream_t stream)
{
    (void)in_sizes; (void)n_in; (void)d_ws; (void)ws_size; (void)out_size;
    const int*   x     = (const int*)  d_in[0];
    const float* emb   = (const float*)d_in[1];
    const float* W_ih  = (const float*)d_in[2];
    const float* W_hh  = (const float*)d_in[3];
    const float* b_ih  = (const float*)d_in[4];
    const float* b_hh  = (const float*)d_in[5];
    const float* W_cls = (const float*)d_in[6];
    const float* b_cls = (const float*)d_in[7];
    float* out = (float*)d_out;

    const int lds_bytes = NV * 16 * 8;  // 128000 <= 163840 (gfx950 opt-in)
    hipFuncSetAttribute((const void*)lstm_fused,
                        hipFuncAttributeMaxDynamicSharedMemorySize, lds_bytes);

    lstm_fused<<<dim3(256), dim3(256), lds_bytes, stream>>>(
        x, emb, W_ih, W_hh, b_ih, b_hh, W_cls, b_cls, out);
}